// Round 1
// baseline (313.621 us; speedup 1.0000x reference)
//
#include <hip/hip_runtime.h>
#include <hip/hip_bf16.h>

// mIoU loss: histogram formulation.
//   pred_count[c]   = #{pred==c}
//   target_count[c] = #{target==c}
//   intersection[c] = #{pred==c && target==c}
//   loss = 1 - mean_c (inter[c]+s) / (pred[c]+tgt[c]-inter[c]+s)
//
// NB fixed at 20 by the problem instance (LDS sized accordingly);
// runtime nb_class/smooth are read on-device in the finalize kernel.

#define NB   20
#define BLK  512
#define GRID 1024

__device__ __forceinline__ void process_pix(int p, int t, unsigned* s_col) {
    // s_col points at s_hist[0*BLK + tid]; rows are class index.
    unsigned m = (unsigned)(p == t);
    // packed fields: bits 0..9 pred_count, 10..19 target_count, 20..29 inter
    s_col[p * BLK] += 1u + (m << 10) + (m << 20);
    if (!m) s_col[t * BLK] += (1u << 10);
}

__global__ __launch_bounds__(BLK, 4) void miou_hist_kernel(
        const int4* __restrict__ preds, const int4* __restrict__ targs,
        unsigned* __restrict__ counts, int n4) {
    __shared__ unsigned s_hist[NB * BLK];
    const int tid = threadIdx.x;

    #pragma unroll
    for (int c = 0; c < NB; ++c) s_hist[c * BLK + tid] = 0u;
    __syncthreads();

    unsigned* s_col = &s_hist[tid];
    int gid    = blockIdx.x * BLK + tid;
    int stride = gridDim.x * BLK;
    for (int i = gid; i < n4; i += stride) {
        int4 pv = preds[i];
        int4 tv = targs[i];
        process_pix(pv.x, tv.x, s_col);
        process_pix(pv.y, tv.y, s_col);
        process_pix(pv.z, tv.z, s_col);
        process_pix(pv.w, tv.w, s_col);
    }
    __syncthreads();

    // Block reduction: wave w handles classes w, w+8, ...
    const int wid  = tid >> 6;
    const int lane = tid & 63;
    for (int c = wid; c < NB; c += (BLK / 64)) {
        unsigned sp = 0, st = 0, si = 0;
        #pragma unroll
        for (int k = 0; k < BLK / 64; ++k) {
            unsigned v = s_hist[c * BLK + k * 64 + lane];
            sp += v & 1023u;
            st += (v >> 10) & 1023u;
            si += (v >> 20) & 1023u;
        }
        #pragma unroll
        for (int off = 32; off > 0; off >>= 1) {
            sp += __shfl_xor(sp, off);
            st += __shfl_xor(st, off);
            si += __shfl_xor(si, off);
        }
        if (lane == 0) {
            atomicAdd(&counts[c],          sp);
            atomicAdd(&counts[NB + c],     st);
            atomicAdd(&counts[2 * NB + c], si);
        }
    }
}

__global__ void miou_finalize_kernel(const unsigned* __restrict__ counts,
                                     const int* __restrict__ nb_ptr,
                                     const int* __restrict__ smooth_ptr,
                                     float* __restrict__ out) {
    const int lane = threadIdx.x;
    const int nb   = *nb_ptr;
    const float s  = (float)(*smooth_ptr);
    float iou = 0.0f;
    if (lane < nb && lane < NB) {
        float inter = (float)counts[2 * NB + lane];
        float pc    = (float)counts[lane];
        float tc    = (float)counts[NB + lane];
        float uni   = pc + tc - inter;
        iou = (inter + s) / (uni + s);
    }
    #pragma unroll
    for (int off = 32; off > 0; off >>= 1) iou += __shfl_xor(iou, off);
    if (lane == 0) out[0] = 1.0f - iou / (float)nb;
}

extern "C" void kernel_launch(void* const* d_in, const int* in_sizes, int n_in,
                              void* d_out, int out_size, void* d_ws, size_t ws_size,
                              hipStream_t stream) {
    const int4* preds      = (const int4*)d_in[0];
    const int4* targs      = (const int4*)d_in[1];
    const int*  nb_ptr     = (const int*)d_in[2];
    const int*  smooth_ptr = (const int*)d_in[3];
    float*      out        = (float*)d_out;

    int n  = in_sizes[0];
    int n4 = n >> 2;  // 16M pixels, divisible by 4

    unsigned* counts = (unsigned*)d_ws;
    hipMemsetAsync(counts, 0, 3 * NB * sizeof(unsigned), stream);

    int grid = GRID;
    int max_grid = (n4 + BLK - 1) / BLK;
    if (grid > max_grid) grid = max_grid;

    miou_hist_kernel<<<grid, BLK, 0, stream>>>(preds, targs, counts, n4);
    miou_finalize_kernel<<<1, 64, 0, stream>>>(counts, nb_ptr, smooth_ptr, out);
}

// Round 2
// 41.932 us; speedup vs baseline: 7.4792x; 7.4792x over previous
//
#include <hip/hip_runtime.h>
#include <hip/hip_bf16.h>

// mIoU loss, histogram formulation, two-stage (no global atomics):
//   Stage 1: per-block privatized LDS histograms -> 60 partial sums per
//            block stored to d_ws[block*64 + {0..59}] (plain stores).
//   Stage 2: one block reduces all partials and computes
//            1 - mean_c (I[c]+s)/(P[c]+T[c]-I[c]+s).
//
// Round-1 lesson: 61k atomicAdds onto 60 addresses serialized to ~313us
// (WRITE_SIZE 1.92MB = 61440 x 32B; duration L3-invariant). Atomics removed.

#define NB    20
#define BLK   512
#define GRIDH 1024
#define PSTRIDE 64   // padded row per block in workspace

__device__ __forceinline__ void process_pix(int p, int t, unsigned* s_col) {
    // s_col = &s_hist[tid]; rows (stride BLK) are class index.
    // packed fields: bits 0..9 pred_count, 10..19 target_count, 20..29 inter
    unsigned m = (unsigned)(p == t);
    s_col[p * BLK] += 1u + (m << 10) + (m << 20);
    if (!m) s_col[t * BLK] += (1u << 10);
}

__global__ __launch_bounds__(BLK, 4) void miou_hist_kernel(
        const int4* __restrict__ preds, const int4* __restrict__ targs,
        unsigned* __restrict__ partials, int n4) {
    __shared__ unsigned s_hist[NB * BLK];
    const int tid = threadIdx.x;

    #pragma unroll
    for (int c = 0; c < NB; ++c) s_hist[c * BLK + tid] = 0u;
    __syncthreads();

    unsigned* s_col = &s_hist[tid];
    const int stride = gridDim.x * BLK;
    int i = blockIdx.x * BLK + tid;

    if (i < n4) {
        int4 pv = preds[i];
        int4 tv = targs[i];
        for (int j = i + stride; j < n4; j += stride) {
            int4 pn = preds[j];   // prefetch next tile: overlaps LDS RMW chain
            int4 tn = targs[j];
            process_pix(pv.x, tv.x, s_col);
            process_pix(pv.y, tv.y, s_col);
            process_pix(pv.z, tv.z, s_col);
            process_pix(pv.w, tv.w, s_col);
            pv = pn; tv = tn;
        }
        process_pix(pv.x, tv.x, s_col);
        process_pix(pv.y, tv.y, s_col);
        process_pix(pv.z, tv.z, s_col);
        process_pix(pv.w, tv.w, s_col);
    }
    __syncthreads();

    // Block reduction: wave w handles classes w, w+8, w+16 (<NB).
    const int wid  = tid >> 6;
    const int lane = tid & 63;
    unsigned* dst = &partials[(size_t)blockIdx.x * PSTRIDE];
    for (int c = wid; c < NB; c += (BLK / 64)) {
        unsigned sp = 0, st = 0, si = 0;
        #pragma unroll
        for (int k = 0; k < BLK / 64; ++k) {
            unsigned v = s_hist[c * BLK + k * 64 + lane];
            sp += v & 1023u;
            st += (v >> 10) & 1023u;
            si += (v >> 20) & 1023u;
        }
        #pragma unroll
        for (int off = 32; off > 0; off >>= 1) {
            sp += __shfl_xor(sp, off);
            st += __shfl_xor(st, off);
            si += __shfl_xor(si, off);
        }
        if (lane == 0) {
            dst[c]          = sp;
            dst[NB + c]     = st;
            dst[2 * NB + c] = si;
        }
    }
}

// One block, 1024 threads. Column col (0..63) summed by 16 sub-threads.
__global__ __launch_bounds__(1024) void miou_reduce_kernel(
        const unsigned* __restrict__ partials, int nblocks,
        const int* __restrict__ nb_ptr, const int* __restrict__ smooth_ptr,
        float* __restrict__ out) {
    __shared__ unsigned s_sum[16][PSTRIDE];
    const int col = threadIdx.x & 63;
    const int sub = threadIdx.x >> 6;

    unsigned acc = 0;
    for (int r = sub; r < nblocks; r += 16)
        acc += partials[(size_t)r * PSTRIDE + col];
    s_sum[sub][col] = acc;
    __syncthreads();

    if (threadIdx.x < PSTRIDE) {
        unsigned tot = 0;
        #pragma unroll
        for (int k = 0; k < 16; ++k) tot += s_sum[k][threadIdx.x];
        s_sum[0][threadIdx.x] = tot;
    }
    __syncthreads();

    if (threadIdx.x == 0) {
        const int   nb = *nb_ptr;
        const float s  = (float)(*smooth_ptr);
        float acc_iou = 0.0f;
        for (int c = 0; c < nb && c < NB; ++c) {
            float pc    = (float)s_sum[0][c];
            float tc    = (float)s_sum[0][NB + c];
            float inter = (float)s_sum[0][2 * NB + c];
            float uni   = pc + tc - inter;
            acc_iou += (inter + s) / (uni + s);
        }
        out[0] = 1.0f - acc_iou / (float)nb;
    }
}

extern "C" void kernel_launch(void* const* d_in, const int* in_sizes, int n_in,
                              void* d_out, int out_size, void* d_ws, size_t ws_size,
                              hipStream_t stream) {
    const int4* preds      = (const int4*)d_in[0];
    const int4* targs      = (const int4*)d_in[1];
    const int*  nb_ptr     = (const int*)d_in[2];
    const int*  smooth_ptr = (const int*)d_in[3];
    float*      out        = (float*)d_out;

    int n  = in_sizes[0];
    int n4 = n >> 2;  // 16M pixels, divisible by 4

    unsigned* partials = (unsigned*)d_ws;

    int grid = GRIDH;
    int max_grid = (n4 + BLK - 1) / BLK;
    if (grid > max_grid) grid = max_grid;
    // keep workspace footprint within ws_size
    size_t need_per_block = PSTRIDE * sizeof(unsigned);
    if ((size_t)grid * need_per_block > ws_size)
        grid = (int)(ws_size / need_per_block);

    miou_hist_kernel<<<grid, BLK, 0, stream>>>(preds, targs, partials, n4);
    miou_reduce_kernel<<<1, 1024, 0, stream>>>(partials, grid, nb_ptr, smooth_ptr, out);
}

// Round 3
// 41.706 us; speedup vs baseline: 7.5198x; 1.0054x over previous
//
#include <hip/hip_runtime.h>
#include <hip/hip_bf16.h>

// mIoU loss, histogram formulation, two-stage (no global atomics):
//   Stage 1: per-block privatized LDS histograms (column-per-thread,
//            conflict-free) -> 60 partial sums per block to d_ws.
//   Stage 2: one block reduces partials, computes 1 - mean IoU.
//
// Round-1 lesson: 61k global atomicAdds onto 60 addresses -> 313us.
// Round-2 lesson: LDS read-modify-write chains (ds_read+add+ds_write with
//   lgkmcnt serialization) left kernel latency-bound at 42us regardless of
//   memory residency. Fix: fire-and-forget LDS atomics (ds_add_u32, no
//   return) + branch-free two-add update per pixel.

#define NB    20
#define BLK   512
#define GRIDH 1024
#define PSTRIDE 64   // padded row per block in workspace

__device__ __forceinline__ void process_pix(int p, int t, unsigned* s_col) {
    // packed fields: bits 0..9 pred_count, 10..19 target_count, 20..29 inter
    unsigned m = (unsigned)(p == t);
    atomicAdd(&s_col[p * BLK], 1u + (m << 20));  // pred count + intersection
    atomicAdd(&s_col[t * BLK], 1u << 10);        // target count (always)
}

__global__ __launch_bounds__(BLK, 4) void miou_hist_kernel(
        const int4* __restrict__ preds, const int4* __restrict__ targs,
        unsigned* __restrict__ partials, int n4) {
    __shared__ unsigned s_hist[NB * BLK];
    const int tid = threadIdx.x;

    #pragma unroll
    for (int c = 0; c < NB; ++c) s_hist[c * BLK + tid] = 0u;
    __syncthreads();

    unsigned* s_col = &s_hist[tid];
    const int stride = gridDim.x * BLK;
    int i = blockIdx.x * BLK + tid;

    if (i < n4) {
        int4 pv = preds[i];
        int4 tv = targs[i];
        for (int j = i + stride; j < n4; j += stride) {
            int4 pn = preds[j];   // prefetch next tile: overlaps ds_add burst
            int4 tn = targs[j];
            process_pix(pv.x, tv.x, s_col);
            process_pix(pv.y, tv.y, s_col);
            process_pix(pv.z, tv.z, s_col);
            process_pix(pv.w, tv.w, s_col);
            pv = pn; tv = tn;
        }
        process_pix(pv.x, tv.x, s_col);
        process_pix(pv.y, tv.y, s_col);
        process_pix(pv.z, tv.z, s_col);
        process_pix(pv.w, tv.w, s_col);
    }
    __syncthreads();

    // Block reduction: wave w handles classes w, w+8, w+16 (<NB).
    const int wid  = tid >> 6;
    const int lane = tid & 63;
    unsigned* dst = &partials[(size_t)blockIdx.x * PSTRIDE];
    for (int c = wid; c < NB; c += (BLK / 64)) {
        unsigned sp = 0, st = 0, si = 0;
        #pragma unroll
        for (int k = 0; k < BLK / 64; ++k) {
            unsigned v = s_hist[c * BLK + k * 64 + lane];
            sp += v & 1023u;
            st += (v >> 10) & 1023u;
            si += (v >> 20) & 1023u;
        }
        #pragma unroll
        for (int off = 32; off > 0; off >>= 1) {
            sp += __shfl_xor(sp, off);
            st += __shfl_xor(st, off);
            si += __shfl_xor(si, off);
        }
        if (lane == 0) {
            dst[c]          = sp;
            dst[NB + c]     = st;
            dst[2 * NB + c] = si;
        }
    }
}

// One block, 1024 threads. Column col (0..63) summed by 16 sub-threads.
__global__ __launch_bounds__(1024) void miou_reduce_kernel(
        const unsigned* __restrict__ partials, int nblocks,
        const int* __restrict__ nb_ptr, const int* __restrict__ smooth_ptr,
        float* __restrict__ out) {
    __shared__ unsigned s_sum[16][PSTRIDE];
    const int col = threadIdx.x & 63;
    const int sub = threadIdx.x >> 6;

    unsigned acc = 0;
    for (int r = sub; r < nblocks; r += 16)
        acc += partials[(size_t)r * PSTRIDE + col];
    s_sum[sub][col] = acc;
    __syncthreads();

    if (threadIdx.x < PSTRIDE) {
        unsigned tot = 0;
        #pragma unroll
        for (int k = 0; k < 16; ++k) tot += s_sum[k][threadIdx.x];
        s_sum[0][threadIdx.x] = tot;
    }
    __syncthreads();

    if (threadIdx.x == 0) {
        const int   nb = *nb_ptr;
        const float s  = (float)(*smooth_ptr);
        float acc_iou = 0.0f;
        for (int c = 0; c < nb && c < NB; ++c) {
            float pc    = (float)s_sum[0][c];
            float tc    = (float)s_sum[0][NB + c];
            float inter = (float)s_sum[0][2 * NB + c];
            float uni   = pc + tc - inter;
            acc_iou += (inter + s) / (uni + s);
        }
        out[0] = 1.0f - acc_iou / (float)nb;
    }
}

extern "C" void kernel_launch(void* const* d_in, const int* in_sizes, int n_in,
                              void* d_out, int out_size, void* d_ws, size_t ws_size,
                              hipStream_t stream) {
    const int4* preds      = (const int4*)d_in[0];
    const int4* targs      = (const int4*)d_in[1];
    const int*  nb_ptr     = (const int*)d_in[2];
    const int*  smooth_ptr = (const int*)d_in[3];
    float*      out        = (float*)d_out;

    int n  = in_sizes[0];
    int n4 = n >> 2;  // 16M pixels, divisible by 4

    unsigned* partials = (unsigned*)d_ws;

    int grid = GRIDH;
    int max_grid = (n4 + BLK - 1) / BLK;
    if (grid > max_grid) grid = max_grid;
    size_t need_per_block = PSTRIDE * sizeof(unsigned);
    if ((size_t)grid * need_per_block > ws_size)
        grid = (int)(ws_size / need_per_block);

    miou_hist_kernel<<<grid, BLK, 0, stream>>>(preds, targs, partials, n4);
    miou_reduce_kernel<<<1, 1024, 0, stream>>>(partials, grid, nb_ptr, smooth_ptr, out);
}